// Round 5
// baseline (342.847 us; speedup 1.0000x reference)
//
#include <hip/hip_runtime.h>
#include <math.h>

// B=8, N=4096, S=512, C=16, D=1024, E=256, H=1024, V=100000
// d_out (float32): [0]=loss, [1..65536]=scores (8,512,16), [65537..69632]=preds

typedef short short8 __attribute__((ext_vector_type(8)));
typedef _Float16 half8v __attribute__((ext_vector_type(8)));
typedef float f32x16 __attribute__((ext_vector_type(16)));

static __device__ inline unsigned short f2bf(float x) {
  unsigned u = __float_as_uint(x);
  unsigned r = (u + 0x7FFFu + ((u >> 16) & 1u)) >> 16;
  return (unsigned short)r;
}
static __device__ inline float bf2f(unsigned short b) {
  return __uint_as_float(((unsigned)b) << 16);
}
static __device__ inline unsigned short f2h(float x) {
  _Float16 h = (_Float16)x;  // v_cvt_f16_f32, RTE
  return *(unsigned short*)&h;
}

#define GLD_TO_LDS(gp, lp)                                          \
  __builtin_amdgcn_global_load_lds(                                 \
      (const __attribute__((address_space(1))) void*)(gp),          \
      (__attribute__((address_space(3))) void*)(lp), 16, 0, 0)

// Split 8 gathered fp32 into bf16 hi/lo and write both LDS regions
// (chunk g -> ushort offset g*8; Alo region at +4096).
static __device__ inline void split_write(unsigned short* buf, int g,
                                          float4 c0, float4 c1) {
  float xs[8] = {c0.x, c0.y, c0.z, c0.w, c1.x, c1.y, c1.z, c1.w};
  short8 h8, l8;
#pragma unroll
  for (int j = 0; j < 8; ++j) {
    unsigned short h = f2bf(xs[j]);
    h8[j] = (short)h;
    l8[j] = (short)f2bf(xs[j] - bf2f(h));
  }
  *(short8*)(buf + (g << 3)) = h8;
  *(short8*)(buf + 4096 + (g << 3)) = l8;
}

// ---------------------------------------------------------------------------
// Fused prep: ent gather -> fp16 A2 (scattered reads off the 102MB table are
// prematerialized at pure BW -- round-4 lesson: in-GEMM gather of >L2 data is
// latency-bound), plus W1 transpose.
//   blocks [0, 16384)       : ent gather -> fp16 A2 (65536 x 256)
//   blocks [16384, 17664)   : W1^T -> sT split-2 bf16 / eT fp16
// ---------------------------------------------------------------------------
__global__ __launch_bounds__(256) void k_prep_e(
    const float* __restrict__ ent, const float* __restrict__ W1,
    const int* __restrict__ linker, const int* __restrict__ cand_all,
    unsigned short* __restrict__ A2, unsigned short* __restrict__ sThi,
    unsigned short* __restrict__ sTlo, unsigned short* __restrict__ eT16) {
  __shared__ float t[32][33];  // only used by the w1t branch
  const int bx = blockIdx.x;
  if (bx < 16384) {
    // ---- ent gather -> fp16.  f indexes float4s of 65536 rows x 256 cols.
    int f = bx * 256 + threadIdx.x;
    int row = f >> 6;        // candidate slot [0, 65536)
    int pair = row >> 4;     // [0, 4096)
    int b = pair >> 9;
    int i = linker[pair];
    int cid = cand_all[(((size_t)b << 12) + (size_t)i) * 16 + (row & 15)];
    const float4 v = *((const float4*)(ent + ((size_t)cid << 8)) + (f & 63));
    *(ushort4*)(A2 + ((size_t)f << 2)) =
        make_ushort4(f2h(v.x), f2h(v.y), f2h(v.z), f2h(v.w));
  } else {
    // ---- W1 (1280x1024) transpose: span part split-2 bf16, ent part fp16.
    int b2x = bx - 16384;           // [0, 1280) = 32 n-tiles x 40 k-tiles
    int n0 = (b2x & 31) * 32, k0 = (b2x >> 5) * 32;
    int rr = threadIdx.x >> 5, cc = threadIdx.x & 31;
#pragma unroll
    for (int i = 0; i < 4; ++i)
      t[rr + 8 * i][cc] = W1[(size_t)(k0 + rr + 8 * i) * 1024 + n0 + cc];
    __syncthreads();
#pragma unroll
    for (int i = 0; i < 4; ++i) {
      int nl = rr + 8 * i;
      float v = t[cc][nl];
      int n = n0 + nl, k = k0 + cc;
      if (k0 < 1024) {
        unsigned short h = f2bf(v);
        unsigned short l = f2bf(v - bf2f(h));
        sThi[(size_t)n * 1024 + k] = h;
        sTlo[(size_t)n * 1024 + k] = l;
      } else {
        eT16[(size_t)n * 256 + (k - 1024)] = f2h(v);
      }
    }
  }
}

// ---------------------------------------------------------------------------
// GEMM1: split-2 bf16 MFMA, 128x128 tile, BK=32, split-K x2 (grid 512).
// A is gathered DIRECTLY from span (per-lane fp32 loads via linker -- L2-
// friendly 16MB working set, compute phase 48 MFMAs covers the latency),
// split to bf16 hi/lo in-register, ds_write'd into the swizzled LDS layout.
// B (W1s^T) staged via global_load_lds from the preconverted split buffers.
// ---------------------------------------------------------------------------
template <int KSTEPS>
__global__ __launch_bounds__(256, 2) void k_g32g(
    const float* __restrict__ span, const int* __restrict__ linker,
    const unsigned short* __restrict__ Bhi, const unsigned short* __restrict__ Blo,
    float* __restrict__ Out) {
  const int tid = threadIdx.x;
  const int l = tid & 63;
  const int w = tid >> 6;        // 0..3
  const int wm = w >> 1, wn = w & 1;
  const int id = blockIdx.x;
  const int z = id >> 8;         // K-split index
  const int sid = id & 255;
  const int m8 = sid & 7;
  const int cb = (sid >> 3) & 7;
  const int q = sid >> 6;
  const int row0 = ((q << 3) + m8) << 7;
  const int col0 = cb << 7;
  const int koff = z * (KSTEPS * 32);
  Out += (size_t)z * 4194304;

  // Two buffers of 16384 ushorts (32KB) each:
  // Ahi[0..4095] | Alo[4096..] | Bhi[8192..] | Blo[12288..]
  __shared__ unsigned short lds[32768];

  f32x16 acc[2][2];
#pragma unroll
  for (int i = 0; i < 2; ++i)
#pragma unroll
    for (int j = 0; j < 2; ++j)
#pragma unroll
      for (int k = 0; k < 16; ++k) acc[i][j][k] = 0.f;

  const int ar0 = tid >> 2, ap0 = tid & 3;
  const int al0c = ap0 ^ ((ar0 >> 1) & 3);
  const int ar1 = ar0 + 64;
  const int al1c = ap0 ^ ((ar1 >> 1) & 3);
  // gathered A source rows (b constant per 128-row tile since 128 | 512)
  const int r0g = row0 + ar0, r1g = row0 + ar1;
  const float* asrc0 =
      span + (((size_t)(r0g >> 9) << 12) + linker[r0g]) * 1024 + koff + al0c * 8;
  const float* asrc1 =
      span + (((size_t)(r1g >> 9) << 12) + linker[r1g]) * 1024 + koff + al1c * 8;
  const size_t boff0 = (size_t)(col0 + ar0) * 1024 + al0c * 8 + koff;
  const size_t boff1 = (size_t)(col0 + ar1) * 1024 + al1c * 8 + koff;
  const int w512 = w * 512;

  // ---- prologue: stage K-step 0 into buffer 0
  {
    float4 a00 = *(const float4*)(asrc0);
    float4 a01 = *(const float4*)(asrc0 + 4);
    float4 a10 = *(const float4*)(asrc1);
    float4 a11 = *(const float4*)(asrc1 + 4);
    GLD_TO_LDS(Bhi + boff0, lds + 8192 + w512);
    GLD_TO_LDS(Bhi + boff1, lds + 10240 + w512);
    GLD_TO_LDS(Blo + boff0, lds + 12288 + w512);
    GLD_TO_LDS(Blo + boff1, lds + 14336 + w512);
    split_write(lds, tid, a00, a01);
    split_write(lds, tid + 256, a10, a11);
  }
  asm volatile("s_waitcnt vmcnt(0) lgkmcnt(0)" ::: "memory");
  __builtin_amdgcn_s_barrier();
  asm volatile("" ::: "memory");

  for (int ks = 0; ks < KSTEPS; ++ks) {
    float4 a00, a01, a10, a11;
    const int k0n = (ks + 1) * 32;
    unsigned short* bn = lds + (((ks + 1) & 1) << 14);
    if (ks + 1 < KSTEPS) {
      a00 = *(const float4*)(asrc0 + k0n);
      a01 = *(const float4*)(asrc0 + k0n + 4);
      a10 = *(const float4*)(asrc1 + k0n);
      a11 = *(const float4*)(asrc1 + k0n + 4);
      GLD_TO_LDS(Bhi + boff0 + k0n, bn + 8192 + w512);
      GLD_TO_LDS(Bhi + boff1 + k0n, bn + 10240 + w512);
      GLD_TO_LDS(Blo + boff0 + k0n, bn + 12288 + w512);
      GLD_TO_LDS(Blo + boff1 + k0n, bn + 14336 + w512);
    }

    const unsigned short* cbuf = lds + ((ks & 1) << 14);
#pragma unroll
    for (int kc = 0; kc < 2; ++kc) {
      const int kg = kc * 2 + (l >> 5);
      short8 ah[2], alv[2], bh[2], bl[2];
#pragma unroll
      for (int it = 0; it < 2; ++it) {
        int r = wm * 64 + it * 32 + (l & 31);
        int off = r * 32 + ((kg ^ ((r >> 1) & 3)) << 3);
        ah[it] = *(const short8*)(cbuf + off);
        alv[it] = *(const short8*)(cbuf + 4096 + off);
      }
#pragma unroll
      for (int jt = 0; jt < 2; ++jt) {
        int r = wn * 64 + jt * 32 + (l & 31);
        int off = r * 32 + ((kg ^ ((r >> 1) & 3)) << 3);
        bh[jt] = *(const short8*)(cbuf + 8192 + off);
        bl[jt] = *(const short8*)(cbuf + 12288 + off);
      }
#pragma unroll
      for (int it = 0; it < 2; ++it)
#pragma unroll
        for (int jt = 0; jt < 2; ++jt) {
          acc[it][jt] = __builtin_amdgcn_mfma_f32_32x32x16_bf16(
              ah[it], bh[jt], acc[it][jt], 0, 0, 0);
          acc[it][jt] = __builtin_amdgcn_mfma_f32_32x32x16_bf16(
              ah[it], bl[jt], acc[it][jt], 0, 0, 0);
          acc[it][jt] = __builtin_amdgcn_mfma_f32_32x32x16_bf16(
              alv[it], bh[jt], acc[it][jt], 0, 0, 0);
        }
    }

    if (ks + 1 < KSTEPS) {
      split_write(bn, tid, a00, a01);
      split_write(bn, tid + 256, a10, a11);
      asm volatile("s_waitcnt vmcnt(0) lgkmcnt(0)" ::: "memory");
      __builtin_amdgcn_s_barrier();
      asm volatile("" ::: "memory");
    }
  }

  // C/D layout (32x32): col = l&31, row = (rg&3) + 8*(rg>>2) + 4*(l>>5)
#pragma unroll
  for (int it = 0; it < 2; ++it) {
    int mb = row0 + wm * 64 + it * 32 + 4 * (l >> 5);
#pragma unroll
    for (int jt = 0; jt < 2; ++jt) {
      int n = col0 + wn * 64 + jt * 32 + (l & 31);
#pragma unroll
      for (int rg = 0; rg < 16; ++rg) {
        int m = mb + (rg & 3) + 8 * (rg >> 2);
        Out[(size_t)m * 1024 + n] = acc[it][jt][rg];
      }
    }
  }
}

// ---------------------------------------------------------------------------
// GEMM2 (round-3 proven form): plain fp16 MFMA (32x32x16_f16), 128x128 tile,
// BK=32, K=256.  A staged via global_load_lds from dense A2 (16KB halves ->
// 32KB LDS -> 4 blocks/CU).  Fused epilogue: relu(acc + (Hs0+Hs1) + b1).W2
// row-sums via LDS transpose-reduce -> per-colblock partials.
// ---------------------------------------------------------------------------
__global__ __launch_bounds__(256, 4) void k_gf16(
    const unsigned short* __restrict__ A,    // fp16 bits, 65536 x 256
    const unsigned short* __restrict__ Bt,   // fp16 bits, 1024 x 256
    const float* __restrict__ HsIn, const float* __restrict__ b1,
    const float* __restrict__ W2, float* __restrict__ Out) {
  const int tid = threadIdx.x;
  const int l = tid & 63;
  const int w = tid >> 6;        // 0..3
  const int wm = w >> 1, wn = w & 1;
  const int id = blockIdx.x;
  const int m8 = id & 7;
  const int cb = (id >> 3) & 7;
  const int q = id >> 6;
  const int row0 = ((q << 3) + m8) << 7;
  const int col0 = cb << 7;

  // Two buffers of 8192 ushorts (16KB) each: A[0..4095] | B[4096..8191]
  __shared__ unsigned short lds[16384];

  f32x16 acc[2][2];
#pragma unroll
  for (int i = 0; i < 2; ++i)
#pragma unroll
    for (int j = 0; j < 2; ++j)
#pragma unroll
      for (int k = 0; k < 16; ++k) acc[i][j][k] = 0.f;

  const int ar0 = tid >> 2, ap0 = tid & 3;
  const int al0c = ap0 ^ ((ar0 >> 1) & 3);
  const int ar1 = (tid + 256) >> 2;
  const int al1c = ap0 ^ ((ar1 >> 1) & 3);
  const size_t aoff0 = (size_t)(row0 + ar0) * 256 + al0c * 8;
  const size_t aoff1 = (size_t)(row0 + ar1) * 256 + al1c * 8;
  const size_t boff0 = (size_t)(col0 + ar0) * 256 + al0c * 8;
  const size_t boff1 = (size_t)(col0 + ar1) * 256 + al1c * 8;
  const int w512 = w * 512;

  // ---- prologue: stage K-step 0 into buffer 0
  GLD_TO_LDS(A + aoff0, lds + w512);
  GLD_TO_LDS(A + aoff1, lds + 2048 + w512);
  GLD_TO_LDS(Bt + boff0, lds + 4096 + w512);
  GLD_TO_LDS(Bt + boff1, lds + 6144 + w512);
  asm volatile("s_waitcnt vmcnt(0)" ::: "memory");
  __builtin_amdgcn_s_barrier();
  asm volatile("" ::: "memory");

#pragma unroll 2
  for (int ks = 0; ks < 8; ++ks) {
    if (ks + 1 < 8) {
      const int k0 = (ks + 1) * 32;
      unsigned short* b = lds + (((ks + 1) & 1) << 13);
      GLD_TO_LDS(A + aoff0 + k0, b + w512);
      GLD_TO_LDS(A + aoff1 + k0, b + 2048 + w512);
      GLD_TO_LDS(Bt + boff0 + k0, b + 4096 + w512);
      GLD_TO_LDS(Bt + boff1 + k0, b + 6144 + w512);
    }

    const unsigned short* cbuf = lds + ((ks & 1) << 13);
#pragma unroll
    for (int kc = 0; kc < 2; ++kc) {
      const int kg = kc * 2 + (l >> 5);
      half8v av[2], bv[2];
#pragma unroll
      for (int it = 0; it < 2; ++it) {
        int r = wm * 64 + it * 32 + (l & 31);
        int off = r * 32 + ((kg ^ ((r >> 1) & 3)) << 3);
        av[it] = *(const half8v*)(cbuf + off);
      }
#pragma unroll
      for (int jt = 0; jt < 2; ++jt) {
        int r = wn * 64 + jt * 32 + (l & 31);
        int off = r * 32 + ((kg ^ ((r >> 1) & 3)) << 3);
        bv[jt] = *(const half8v*)(cbuf + 4096 + off);
      }
#pragma unroll
      for (int it = 0; it < 2; ++it)
#pragma unroll
        for (int jt = 0; jt < 2; ++jt)
          acc[it][jt] = __builtin_amdgcn_mfma_f32_32x32x16_f16(
              av[it], bv[jt], acc[it][jt], 0, 0, 0);
    }

    if (ks + 1 < 8) {
      asm volatile("s_waitcnt vmcnt(0)" ::: "memory");
      __builtin_amdgcn_s_barrier();
      asm volatile("" ::: "memory");
    }
  }

  // Fused epilogue: per-lane partial scores, then LDS transpose-reduce.
  float sv[2][16];
#pragma unroll
  for (int it = 0; it < 2; ++it) {
#pragma unroll
    for (int rg = 0; rg < 16; ++rg) sv[it][rg] = 0.f;
    const int p0 = (row0 + wm * 64 + it * 32) >> 4;  // 16-row pair index
#pragma unroll
    for (int jt = 0; jt < 2; ++jt) {
      int n = col0 + wn * 64 + jt * 32 + (l & 31);
      float b1v = b1[n], w2v = W2[n];
      // sum the two split-K partials of Hs
      float add0 = HsIn[(size_t)p0 * 1024 + n] +
                   HsIn[4194304 + (size_t)p0 * 1024 + n] + b1v;  // rows 0..15
      float add1 = HsIn[(size_t)(p0 + 1) * 1024 + n] +
                   HsIn[4194304 + (size_t)(p0 + 1) * 1024 + n] + b1v;  // 16..31
#pragma unroll
      for (int rg = 0; rg < 16; ++rg) {
        float h = fmaxf(acc[it][jt][rg] + (rg < 8 ? add0 : add1), 0.f);
        sv[it][rg] = fmaf(h, w2v, sv[it][rg]);
      }
    }
  }
  __syncthreads();  // K-loop LDS reads complete; reuse lds as f32 scratch
  float* scf = (float*)lds;  // [8 slots][32 rows][32 cols], rotation-swizzled
  const int cc0 = l & 31, lh4 = 4 * (l >> 5);
#pragma unroll
  for (int it = 0; it < 2; ++it)
#pragma unroll
    for (int rg = 0; rg < 16; ++rg) {
      int row = (rg & 3) + 8 * (rg >> 2) + lh4;  // 0..31 within tile
      scf[((w * 2 + it) * 32 + row) * 32 + ((cc0 + row) & 31)] = sv[it][rg];
    }
  __syncthreads();
  // 256 threads: 2 per global row gr (halves of 32 cols), sum wn=0 + wn=1.
  int gr = tid >> 1, h = tid & 1;
  int r = gr & 31, itv = (gr >> 5) & 1, wmv = gr >> 6;
  const float* sa = scf + ((wmv * 4 + itv) * 32 + r) * 32;      // wn=0 slot
  const float* sb = scf + ((wmv * 4 + 2 + itv) * 32 + r) * 32;  // wn=1 slot
  float sum = 0.f;
#pragma unroll
  for (int j = 0; j < 16; ++j) {
    int cidx = (h * 16 + j + r) & 31;
    sum += sa[cidx] + sb[cidx];
  }
  sum += __shfl_xor(sum, 1, 64);
  if (h == 0) Out[(size_t)cb * 65536 + row0 + gr] = sum;
}

// ---------------------------------------------------------------------------
// Finalize: sum 8 col-block partials (float4 loads), +b2; masked BCE loss;
// argmax preds.  64 blocks x 64 threads.
// ---------------------------------------------------------------------------
__global__ __launch_bounds__(64) void k_final8(const float* __restrict__ score8,
                                               const float* __restrict__ b2p,
                                               const float* __restrict__ targets_all,
                                               const int* __restrict__ linker,
                                               const int* __restrict__ len_all,
                                               float* __restrict__ out) {
  int p = blockIdx.x * 64 + threadIdx.x;  // [0, 4096)
  float b2 = b2p[0];
  int b = p >> 9;
  int i = linker[p];
  int len = len_all[(b << 12) + i];
  const float* tg = targets_all + ((((size_t)b << 12) + (size_t)i) << 4);

  float sc[16];
#pragma unroll
  for (int c = 0; c < 16; ++c) sc[c] = b2;
#pragma unroll
  for (int c8 = 0; c8 < 8; ++c8) {
    const float4* q4 = (const float4*)(score8 + (size_t)c8 * 65536 + p * 16);
#pragma unroll
    for (int j = 0; j < 4; ++j) {
      float4 v = q4[j];
      sc[j * 4 + 0] += v.x; sc[j * 4 + 1] += v.y;
      sc[j * 4 + 2] += v.z; sc[j * 4 + 3] += v.w;
    }
  }

  float loss = 0.f;
  float best = -INFINITY;
  int bc = 0;
#pragma unroll
  for (int c = 0; c < 16; ++c) {
    float s = sc[c];
    out[1 + p * 16 + c] = s;
    float val;
    if (c < len) {
      float t = tg[c];
      loss += fmaxf(s, 0.f) - s * t + log1pf(expf(-fabsf(s)));
      val = s;
    } else {
      val = s - 1e23f;
    }
    if (val > best) { best = val; bc = c; }
  }
  out[1 + 65536 + p] = (float)bc;

  for (int off = 32; off > 0; off >>= 1) loss += __shfl_down(loss, off, 64);
  if (threadIdx.x == 0) atomicAdd(out, loss);
}

// ===========================================================================
// Fallback fp32 path (round-1, proven) — used if ws_size is too small.
// ===========================================================================
#define BM 128
#define BN 128
#define BK 16
#define PAD 4

__global__ __launch_bounds__(256) void k_prep(const int* __restrict__ linker,
                                              const int* __restrict__ cand_all,
                                              int* __restrict__ cand_ids) {
  int g = blockIdx.x * 256 + threadIdx.x;
  int pair = g >> 4;
  int c = g & 15;
  int b = pair >> 9;
  int i = linker[pair];
  cand_ids[g] = cand_all[(((size_t)b << 12) + (size_t)i) * 16 + c];
}

__global__ __launch_bounds__(256) void k_hs(const float* __restrict__ span,
                                            const float* __restrict__ W1,
                                            const int* __restrict__ linker,
                                            float* __restrict__ Hs) {
  const int tid = threadIdx.x;
  const int tx = tid & 15, ty = tid >> 4;
  const int row0 = blockIdx.y * BM;
  const int col0 = blockIdx.x * BN;
  __shared__ float As[BK][BM + PAD];
  __shared__ float Bs[BK][BN + PAD];
  __shared__ int rows_g[BM];
  if (tid < BM) {
    int m = row0 + tid;
    int b = m >> 9;
    rows_g[tid] = (b << 12) + linker[m];
  }
  __syncthreads();
  float acc[8][8] = {};
  for (int k0 = 0; k0 < 1024; k0 += BK) {
#pragma unroll
    for (int ll = 0; ll < 2; ++ll) {
      int f = tid + ll * 256;
      int r = f >> 2;
      int kk = (f & 3) << 2;
      const float4 v = *(const float4*)(span + (size_t)rows_g[r] * 1024 + k0 + kk);
      As[kk + 0][r] = v.x; As[kk + 1][r] = v.y;
      As[kk + 2][r] = v.z; As[kk + 3][r] = v.w;
    }
#pragma unroll
    for (int ll = 0; ll < 2; ++ll) {
      int f = tid + ll * 256;
      int kk = f >> 5;
      int nn = (f & 31) << 2;
      *(float4*)&Bs[kk][nn] = *(const float4*)(W1 + (size_t)(k0 + kk) * 1024 + col0 + nn);
    }
    __syncthreads();
#pragma unroll
    for (int k = 0; k < BK; ++k) {
      float a[8], b[8];
      *(float4*)&a[0] = *(const float4*)&As[k][ty * 8];
      *(float4*)&a[4] = *(const float4*)&As[k][ty * 8 + 4];
      *(float4*)&b[0] = *(const float4*)&Bs[k][tx * 8];
      *(float4*)&b[4] = *(const float4*)&Bs[k][tx * 8 + 4];
#pragma unroll
      for (int i = 0; i < 8; ++i)
#pragma unroll
        for (int j = 0; j < 8; ++j) acc[i][j] = fmaf(a[i], b[j], acc[i][j]);
    }
    __syncthreads();
  }
#pragma unroll
  for (int i = 0; i < 8; ++i) {
    int m = row0 + ty * 8 + i;
    float* dst = Hs + (size_t)m * 1024 + col0 + tx * 8;
    *(float4*)dst = *(float4*)&acc[i][0];
    *(float4*)(dst + 4) = *(float4*)&acc[i][4];
  }
}

__global__ __launch_bounds__(256) void k_hc(const float* __restrict__ ent,
                                            const float* __restrict__ W1,
                                            const int* __restrict__ cand_ids,
                                            const float* __restrict__ Hs,
                                            const float* __restrict__ b1,
                                            const float* __restrict__ W2,
                                            float* __restrict__ score_ws) {
  const int tid = threadIdx.x;
  const int tx = tid & 15, ty = tid >> 4;
  const int row0 = blockIdx.y * BM;
  const int col0 = blockIdx.x * BN;
  __shared__ float As[BK][BM + PAD];
  __shared__ float Bs[BK][BN + PAD];
  __shared__ int rows_g[BM];
  __shared__ float red[BM][17];
  if (tid < BM) rows_g[tid] = cand_ids[row0 + tid];
  __syncthreads();
  float acc[8][8] = {};
  for (int k0 = 0; k0 < 256; k0 += BK) {
#pragma unroll
    for (int ll = 0; ll < 2; ++ll) {
      int f = tid + ll * 256;
      int r = f >> 2;
      int kk = (f & 3) << 2;
      const float4 v = *(const float4*)(ent + (size_t)rows_g[r] * 256 + k0 + kk);
      As[kk + 0][r] = v.x; As[kk + 1][r] = v.y;
      As[kk + 2][r] = v.z; As[kk + 3][r] = v.w;
    }
#pragma unroll
    for (int ll = 0; ll < 2; ++ll) {
      int f = tid + ll * 256;
      int kk = f >> 5;
      int nn = (f & 31) << 2;
      *(float4*)&Bs[kk][nn] =
          *(const float4*)(W1 + (size_t)(1024 + k0 + kk) * 1024 + col0 + nn);
    }
    __syncthreads();
#pragma unroll
    for (int k = 0; k < BK; ++k) {
      float a[8], b[8];
      *(float4*)&a[0] = *(const float4*)&As[k][ty * 8];
      *(float4*)&a[4] = *(const float4*)&As[k][ty * 8 + 4];
      *(float4*)&b[0] = *(const float4*)&Bs[k][tx * 8];
      *(float4*)&b[4] = *(const float4*)&Bs[k][tx * 8 + 4];
#pragma unroll
      for (int i = 0; i < 8; ++i)
#pragma unroll
        for (int j = 0; j < 8; ++j) acc[i][j] = fmaf(a[i], b[j], acc[i][j]);
    }
    __syncthreads();
  }
  const int pair = (row0 + ty * 8) >> 4;
  float hsv[8], b1v[8], w2v[8];
  {
    const float* hp = Hs + (size_t)pair * 1024 + col0 + tx * 8;
    *(float4*)&hsv[0] = *(const float4*)hp;
    *(float4*)&hsv[4] = *(const float4*)(hp + 4);
    const float* bp = b1 + col0 + tx * 8;
    *(float4*)&b1v[0] = *(const float4*)bp;
    *(float4*)&b1v[4] = *(const float4*)(bp + 4);
    const float* wp = W2 + col0 + tx * 8;
    *(float4*)&w2v[0] = *(const float4*)wp;
    *(float4*)&w2v[4] = *(const float4*)(wp + 4);
  }
#pragma unroll
  for (int i = 0; i < 8; ++i) {
    float s = 0.f;
#pragma unroll
    for (int j = 0; j < 8; ++j) {
      float h = acc[i][j] + hsv[j] + b1v[j];
      h = fmaxf(h, 0.f);
      s = fmaf(h, w2v[j], s);
    }
    red[ty * 8 + i][tx] = s;
  }
  __syncthreads();
  if (tid < BM) {
    float s = 0.f;
#pragma unroll
    for (int x = 0; x < 16; ++x) s += red[tid][x];
    atomicAdd(&score_ws[row0 + tid], s);
  }
}

__global__ __launch_bounds__(256) void k_final(const float* __restrict__ score_ws,
                                               const float* __restrict__ b2p,
                                               const float* __restrict__ targets_all,
                                               const int* __restrict__ linker,
                                               const int* __restrict__ len_all,
                                               float* __restrict__ out) {
  int p = blockIdx.x * 256 + threadIdx.x;  // [0, 4096)
  float b2 = b2p[0];
  int b = p >> 9;
  int i = linker[p];
  int len = len_all[(b << 12) + i];
  const float* tg = targets_all + ((((size_t)b << 12) + (size_t)i) << 4);

  float loss = 0.f;
  float best = -INFINITY;
  int bc = 0;
#pragma unroll
  for (int c = 0; c < 16; ++c) {
    float sc = score_ws[p * 16 + c] + b2;
    out[1 + p * 16 + c] = sc;
    float val;
    if (c < len) {
      float t = tg[c];
      loss += fmaxf(sc, 0.f) - sc * t + log1pf(expf(-fabsf(sc)));
      val = sc;
    } else {
      val = sc - 1e23f;
    }
    if (val > best) { best = val; bc = c; }
  }
  out[1 + 65536 + p] = (float)bc;

  for (int off = 32; off > 0; off >>= 1) loss += __shfl_down(loss, off, 64);
  if ((threadIdx.x & 63) == 0) atomicAdd(out, loss);
}

// ===========================================================================
extern "C" void kernel_launch(void* const* d_in, const int* in_sizes, int n_in,
                              void* d_out, int out_size, void* d_ws,
                              size_t ws_size, hipStream_t stream) {
  const float* span    = (const float*)d_in[0];
  const float* ent     = (const float*)d_in[1];
  const float* W1      = (const float*)d_in[2];
  const float* b1      = (const float*)d_in[3];
  const float* W2      = (const float*)d_in[4];
  const float* b2      = (const float*)d_in[5];
  const float* targets = (const float*)d_in[6];
  const int* linker    = (const int*)d_in[7];
  const int* cand_all  = (const int*)d_in[8];
  const int* len_all   = (const int*)d_in[9];
  float* out = (float*)d_out;

  char* ws = (char*)d_ws;
  float* Hs       = (float*)(ws + 0);                  // 33,554,432 (2 split-K partials)
  float* score8   = (float*)(ws + 33554432);           //  2,097,152
  unsigned short* A2   = (unsigned short*)(ws + 35651584);  // 33,554,432 (fp16)
  unsigned short* sTh  = (unsigned short*)(ws + 69206016);  //  2,097,152
  unsigned short* sTl  = (unsigned short*)(ws + 71303168);  //  2,097,152
  unsigned short* eT16 = (unsigned short*)(ws + 73400320);  //    524,288 (fp16)
  float* score_ws = (float*)(ws + 73924608);           //    262,144 (fallback)
  int* cand_ids   = (int*)(ws + 74186752);             //    262,144 (fallback)
  const size_t NEED_MFMA = 74448896;

  hipMemsetAsync(d_out, 0, sizeof(float), stream);

  if (ws_size >= NEED_MFMA) {
    // prep: ent gather -> fp16 A2 (BW-bound prematerialization) + W1^T
    k_prep_e<<<dim3(17664), dim3(256), 0, stream>>>(
        ent, W1, linker, cand_all, A2, sTh, sTl, eT16);
    // GEMM1: Hs partials = gather(span)@W1s, split-2 bf16, split-K x2
    k_g32g<16><<<dim3(512), dim3(256), 0, stream>>>(span, linker, sTh, sTl, Hs);
    // GEMM2: A2@W1e fp16 + relu + W2 row-sums (round-3 proven structure)
    k_gf16<<<dim3(4096), dim3(256), 0, stream>>>(A2, eT16, Hs, b1, W2, score8);
    k_final8<<<dim3(64), dim3(64), 0, stream>>>(score8, b2, targets, linker,
                                                len_all, out);
  } else {
    hipMemsetAsync(score_ws, 0, 65536 * sizeof(float), stream);
    k_prep<<<dim3(256), dim3(256), 0, stream>>>(linker, cand_all, cand_ids);
    dim3 g1(8, 32);
    k_hs<<<g1, dim3(256), 0, stream>>>(span, W1, linker, Hs);
    dim3 g2(8, 512);
    k_hc<<<g2, dim3(256), 0, stream>>>(ent, W1, cand_ids, Hs, b1, W2, score_ws);
    k_final<<<dim3(16), dim3(256), 0, stream>>>(score_ws, b2, targets, linker,
                                                len_all, out);
  }
}

// Round 6
// 330.908 us; speedup vs baseline: 1.0361x; 1.0361x over previous
//
#include <hip/hip_runtime.h>
#include <math.h>

// B=8, N=4096, S=512, C=16, D=1024, E=256, H=1024, V=100000
// d_out (float32): [0]=loss, [1..65536]=scores (8,512,16), [65537..69632]=preds

typedef short short8 __attribute__((ext_vector_type(8)));
typedef _Float16 half8v __attribute__((ext_vector_type(8)));
typedef float f32x16 __attribute__((ext_vector_type(16)));

static __device__ inline unsigned short f2bf(float x) {
  unsigned u = __float_as_uint(x);
  unsigned r = (u + 0x7FFFu + ((u >> 16) & 1u)) >> 16;
  return (unsigned short)r;
}
static __device__ inline float bf2f(unsigned short b) {
  return __uint_as_float(((unsigned)b) << 16);
}
static __device__ inline unsigned short f2h(float x) {
  _Float16 h = (_Float16)x;  // v_cvt_f16_f32, RTE
  return *(unsigned short*)&h;
}

#define GLD_TO_LDS(gp, lp)                                          \
  __builtin_amdgcn_global_load_lds(                                 \
      (const __attribute__((address_space(1))) void*)(gp),          \
      (__attribute__((address_space(3))) void*)(lp), 16, 0, 0)

// Split 8 gathered fp32 into bf16 hi/lo and write both LDS regions
// (chunk g -> ushort offset g*8; Alo region at +4096).
static __device__ inline void split_write(unsigned short* buf, int g,
                                          float4 c0, float4 c1) {
  float xs[8] = {c0.x, c0.y, c0.z, c0.w, c1.x, c1.y, c1.z, c1.w};
  short8 h8, l8;
#pragma unroll
  for (int j = 0; j < 8; ++j) {
    unsigned short h = f2bf(xs[j]);
    h8[j] = (short)h;
    l8[j] = (short)f2bf(xs[j] - bf2f(h));
  }
  *(short8*)(buf + (g << 3)) = h8;
  *(short8*)(buf + 4096 + (g << 3)) = l8;
}

// ---------------------------------------------------------------------------
// Fused prep: ent gather -> fp16 A2 (scattered reads off the 102MB table are
// prematerialized at pure BW -- round-4 lesson: in-GEMM gather of >L2 data is
// latency-bound), plus W1 transpose.
//   blocks [0, 16384)       : ent gather -> fp16 A2 (65536 x 256)
//   blocks [16384, 17664)   : W1^T -> sT split-2 bf16 / eT fp16
// ---------------------------------------------------------------------------
__global__ __launch_bounds__(256) void k_prep_e(
    const float* __restrict__ ent, const float* __restrict__ W1,
    const int* __restrict__ linker, const int* __restrict__ cand_all,
    unsigned short* __restrict__ A2, unsigned short* __restrict__ sThi,
    unsigned short* __restrict__ sTlo, unsigned short* __restrict__ eT16) {
  __shared__ float t[32][33];  // only used by the w1t branch
  const int bx = blockIdx.x;
  if (bx < 16384) {
    // ---- ent gather -> fp16.  f indexes float4s of 65536 rows x 256 cols.
    int f = bx * 256 + threadIdx.x;
    int row = f >> 6;        // candidate slot [0, 65536)
    int pair = row >> 4;     // [0, 4096)
    int b = pair >> 9;
    int i = linker[pair];
    int cid = cand_all[(((size_t)b << 12) + (size_t)i) * 16 + (row & 15)];
    const float4 v = *((const float4*)(ent + ((size_t)cid << 8)) + (f & 63));
    *(ushort4*)(A2 + ((size_t)f << 2)) =
        make_ushort4(f2h(v.x), f2h(v.y), f2h(v.z), f2h(v.w));
  } else {
    // ---- W1 (1280x1024) transpose: span part split-2 bf16, ent part fp16.
    int b2x = bx - 16384;           // [0, 1280) = 32 n-tiles x 40 k-tiles
    int n0 = (b2x & 31) * 32, k0 = (b2x >> 5) * 32;
    int rr = threadIdx.x >> 5, cc = threadIdx.x & 31;
#pragma unroll
    for (int i = 0; i < 4; ++i)
      t[rr + 8 * i][cc] = W1[(size_t)(k0 + rr + 8 * i) * 1024 + n0 + cc];
    __syncthreads();
#pragma unroll
    for (int i = 0; i < 4; ++i) {
      int nl = rr + 8 * i;
      float v = t[cc][nl];
      int n = n0 + nl, k = k0 + cc;
      if (k0 < 1024) {
        unsigned short h = f2bf(v);
        unsigned short l = f2bf(v - bf2f(h));
        sThi[(size_t)n * 1024 + k] = h;
        sTlo[(size_t)n * 1024 + k] = l;
      } else {
        eT16[(size_t)n * 256 + (k - 1024)] = f2h(v);
      }
    }
  }
}

// ---------------------------------------------------------------------------
// GEMM1: split-2 bf16 MFMA, 128x128 tile, BK=32, split-K x2 (grid 512).
// A is gathered DIRECTLY from span (per-lane fp32 loads via linker -- L2-
// friendly 16MB working set, compute phase 48 MFMAs covers the latency),
// split to bf16 hi/lo in-register, ds_write'd into the swizzled LDS layout.
// B (W1s^T) staged via global_load_lds from the preconverted split buffers.
// ---------------------------------------------------------------------------
template <int KSTEPS>
__global__ __launch_bounds__(256, 2) void k_g32g(
    const float* __restrict__ span, const int* __restrict__ linker,
    const unsigned short* __restrict__ Bhi, const unsigned short* __restrict__ Blo,
    float* __restrict__ Out) {
  const int tid = threadIdx.x;
  const int l = tid & 63;
  const int w = tid >> 6;        // 0..3
  const int wm = w >> 1, wn = w & 1;
  const int id = blockIdx.x;
  const int z = id >> 8;         // K-split index
  const int sid = id & 255;
  const int m8 = sid & 7;
  const int cb = (sid >> 3) & 7;
  const int q = sid >> 6;
  const int row0 = ((q << 3) + m8) << 7;
  const int col0 = cb << 7;
  const int koff = z * (KSTEPS * 32);
  Out += (size_t)z * 4194304;

  // Two buffers of 16384 ushorts (32KB) each:
  // Ahi[0..4095] | Alo[4096..] | Bhi[8192..] | Blo[12288..]
  __shared__ unsigned short lds[32768];

  f32x16 acc[2][2];
#pragma unroll
  for (int i = 0; i < 2; ++i)
#pragma unroll
    for (int j = 0; j < 2; ++j)
#pragma unroll
      for (int k = 0; k < 16; ++k) acc[i][j][k] = 0.f;

  const int ar0 = tid >> 2, ap0 = tid & 3;
  const int al0c = ap0 ^ ((ar0 >> 1) & 3);
  const int ar1 = ar0 + 64;
  const int al1c = ap0 ^ ((ar1 >> 1) & 3);
  // gathered A source rows (b constant per 128-row tile since 128 | 512)
  const int r0g = row0 + ar0, r1g = row0 + ar1;
  const float* asrc0 =
      span + (((size_t)(r0g >> 9) << 12) + linker[r0g]) * 1024 + koff + al0c * 8;
  const float* asrc1 =
      span + (((size_t)(r1g >> 9) << 12) + linker[r1g]) * 1024 + koff + al1c * 8;
  const size_t boff0 = (size_t)(col0 + ar0) * 1024 + al0c * 8 + koff;
  const size_t boff1 = (size_t)(col0 + ar1) * 1024 + al1c * 8 + koff;
  const int w512 = w * 512;

  // ---- prologue: stage K-step 0 into buffer 0
  {
    float4 a00 = *(const float4*)(asrc0);
    float4 a01 = *(const float4*)(asrc0 + 4);
    float4 a10 = *(const float4*)(asrc1);
    float4 a11 = *(const float4*)(asrc1 + 4);
    GLD_TO_LDS(Bhi + boff0, lds + 8192 + w512);
    GLD_TO_LDS(Bhi + boff1, lds + 10240 + w512);
    GLD_TO_LDS(Blo + boff0, lds + 12288 + w512);
    GLD_TO_LDS(Blo + boff1, lds + 14336 + w512);
    split_write(lds, tid, a00, a01);
    split_write(lds, tid + 256, a10, a11);
  }
  asm volatile("s_waitcnt vmcnt(0) lgkmcnt(0)" ::: "memory");
  __builtin_amdgcn_s_barrier();
  asm volatile("" ::: "memory");

  for (int ks = 0; ks < KSTEPS; ++ks) {
    float4 a00, a01, a10, a11;
    const int k0n = (ks + 1) * 32;
    unsigned short* bn = lds + (((ks + 1) & 1) << 14);
    if (ks + 1 < KSTEPS) {
      a00 = *(const float4*)(asrc0 + k0n);
      a01 = *(const float4*)(asrc0 + k0n + 4);
      a10 = *(const float4*)(asrc1 + k0n);
      a11 = *(const float4*)(asrc1 + k0n + 4);
      GLD_TO_LDS(Bhi + boff0 + k0n, bn + 8192 + w512);
      GLD_TO_LDS(Bhi + boff1 + k0n, bn + 10240 + w512);
      GLD_TO_LDS(Blo + boff0 + k0n, bn + 12288 + w512);
      GLD_TO_LDS(Blo + boff1 + k0n, bn + 14336 + w512);
    }

    const unsigned short* cbuf = lds + ((ks & 1) << 14);
#pragma unroll
    for (int kc = 0; kc < 2; ++kc) {
      const int kg = kc * 2 + (l >> 5);
      short8 ah[2], alv[2], bh[2], bl[2];
#pragma unroll
      for (int it = 0; it < 2; ++it) {
        int r = wm * 64 + it * 32 + (l & 31);
        int off = r * 32 + ((kg ^ ((r >> 1) & 3)) << 3);
        ah[it] = *(const short8*)(cbuf + off);
        alv[it] = *(const short8*)(cbuf + 4096 + off);
      }
#pragma unroll
      for (int jt = 0; jt < 2; ++jt) {
        int r = wn * 64 + jt * 32 + (l & 31);
        int off = r * 32 + ((kg ^ ((r >> 1) & 3)) << 3);
        bh[jt] = *(const short8*)(cbuf + 8192 + off);
        bl[jt] = *(const short8*)(cbuf + 12288 + off);
      }
#pragma unroll
      for (int it = 0; it < 2; ++it)
#pragma unroll
        for (int jt = 0; jt < 2; ++jt) {
          acc[it][jt] = __builtin_amdgcn_mfma_f32_32x32x16_bf16(
              ah[it], bh[jt], acc[it][jt], 0, 0, 0);
          acc[it][jt] = __builtin_amdgcn_mfma_f32_32x32x16_bf16(
              ah[it], bl[jt], acc[it][jt], 0, 0, 0);
          acc[it][jt] = __builtin_amdgcn_mfma_f32_32x32x16_bf16(
              alv[it], bh[jt], acc[it][jt], 0, 0, 0);
        }
    }

    if (ks + 1 < KSTEPS) {
      split_write(bn, tid, a00, a01);
      split_write(bn, tid + 256, a10, a11);
      asm volatile("s_waitcnt vmcnt(0) lgkmcnt(0)" ::: "memory");
      __builtin_amdgcn_s_barrier();
      asm volatile("" ::: "memory");
    }
  }

  // C/D layout (32x32): col = l&31, row = (rg&3) + 8*(rg>>2) + 4*(l>>5)
#pragma unroll
  for (int it = 0; it < 2; ++it) {
    int mb = row0 + wm * 64 + it * 32 + 4 * (l >> 5);
#pragma unroll
    for (int jt = 0; jt < 2; ++jt) {
      int n = col0 + wn * 64 + jt * 32 + (l & 31);
#pragma unroll
      for (int rg = 0; rg < 16; ++rg) {
        int m = mb + (rg & 3) + 8 * (rg >> 2);
        Out[(size_t)m * 1024 + n] = acc[it][jt][rg];
      }
    }
  }
}

// ---------------------------------------------------------------------------
// GEMM2 v2: plain fp16 MFMA (32x32x16_f16), 256x128 tile, BK=32, K=256.
// Waves 4x1: wave w owns rows [w*64, w*64+64) x all 128 cols -> 16 MFMAs per
// K-step (2x the old 128x128 tile) between barrier drains; no wn split so the
// epilogue reduce needs only 8 LDS slots.  LDS 2 x 24KB = 48KB -> 3 blocks/CU.
// A staged via global_load_lds from dense A2; fused epilogue:
// relu(acc + (Hs0+Hs1) + b1).W2 row-sums -> per-colblock partials.
// Grid 2048 (256 row-tiles x 8 col-blocks), XCD-swizzled (id%8 = row-tile low
// bits so the 8 col-blocks of a row-tile share an XCD -> A panel L2 reuse).
// ---------------------------------------------------------------------------
__global__ __launch_bounds__(256, 3) void k_gf16(
    const unsigned short* __restrict__ A,    // fp16 bits, 65536 x 256
    const unsigned short* __restrict__ Bt,   // fp16 bits, 1024 x 256
    const float* __restrict__ HsIn, const float* __restrict__ b1,
    const float* __restrict__ W2, float* __restrict__ Out) {
  const int tid = threadIdx.x;
  const int l = tid & 63;
  const int w = tid >> 6;        // 0..3, wave owns rows w*64..w*64+63
  const int id = blockIdx.x;
  const int m8 = id & 7;
  const int cb = (id >> 3) & 7;
  const int q = id >> 6;         // 0..31
  const int row0 = ((q << 3) + m8) << 8;   // 256-row tile
  const int col0 = cb << 7;

  // Two buffers of 12288 ushorts (24KB): A[0..8191] | B[8192..12287]
  __shared__ unsigned short lds[24576];

  f32x16 acc[2][4];
#pragma unroll
  for (int i = 0; i < 2; ++i)
#pragma unroll
    for (int j = 0; j < 4; ++j)
#pragma unroll
      for (int k = 0; k < 16; ++k) acc[i][j][k] = 0.f;

  // Chunk swizzle: chunk g covers row r=g>>2, logical K-slot c = (g&3)^((r>>1)&3).
  // (r -> r+64 leaves ((r>>1)&3) unchanged, so one c serves all 4 A chunks.)
  const int ar = tid >> 2, ap = tid & 3;
  const int ac = ap ^ ((ar >> 1) & 3);
  const size_t abase = (size_t)(row0 + ar) * 256 + ac * 8;  // +16384 per +64 rows
  const size_t bbase = (size_t)(col0 + ar) * 256 + ac * 8;
  const int w512 = w * 512;

#define STAGE2(buf, ks32)                                        \
  do {                                                           \
    GLD_TO_LDS(A + abase + (ks32), (buf) + w512);                \
    GLD_TO_LDS(A + abase + 16384 + (ks32), (buf) + 2048 + w512); \
    GLD_TO_LDS(A + abase + 32768 + (ks32), (buf) + 4096 + w512); \
    GLD_TO_LDS(A + abase + 49152 + (ks32), (buf) + 6144 + w512); \
    GLD_TO_LDS(Bt + bbase + (ks32), (buf) + 8192 + w512);        \
    GLD_TO_LDS(Bt + bbase + 16384 + (ks32), (buf) + 10240 + w512);\
  } while (0)

  // ---- prologue: stage K-step 0 into buffer 0
  STAGE2(lds, 0);
  asm volatile("s_waitcnt vmcnt(0)" ::: "memory");
  __builtin_amdgcn_s_barrier();
  asm volatile("" ::: "memory");

#pragma unroll 2
  for (int ks = 0; ks < 8; ++ks) {
    if (ks + 1 < 8) {
      unsigned short* bn = lds + ((ks + 1) & 1) * 12288;
      STAGE2(bn, (ks + 1) * 32);
    }

    const unsigned short* cbuf = lds + (ks & 1) * 12288;
#pragma unroll
    for (int kc = 0; kc < 2; ++kc) {
      const int kg = kc * 2 + (l >> 5);
      half8v av[2], bv[4];
#pragma unroll
      for (int it = 0; it < 2; ++it) {
        int r = w * 64 + it * 32 + (l & 31);
        int off = r * 32 + ((kg ^ ((r >> 1) & 3)) << 3);
        av[it] = *(const half8v*)(cbuf + off);
      }
#pragma unroll
      for (int jt = 0; jt < 4; ++jt) {
        int r = jt * 32 + (l & 31);
        int off = 8192 + r * 32 + ((kg ^ ((r >> 1) & 3)) << 3);
        bv[jt] = *(const half8v*)(cbuf + off);
      }
#pragma unroll
      for (int it = 0; it < 2; ++it)
#pragma unroll
        for (int jt = 0; jt < 4; ++jt)
          acc[it][jt] = __builtin_amdgcn_mfma_f32_32x32x16_f16(
              av[it], bv[jt], acc[it][jt], 0, 0, 0);
    }

    if (ks + 1 < 8) {
      asm volatile("s_waitcnt vmcnt(0)" ::: "memory");
      __builtin_amdgcn_s_barrier();
      asm volatile("" ::: "memory");
    }
  }
#undef STAGE2

  // Fused epilogue: per-lane partial scores (summed over this lane's 4 jt
  // cols), then LDS transpose-reduce (8 slots x 32 rows x 32 cols, rotation-
  // swizzled).  C/D: col = l&31, row = (rg&3)+8*(rg>>2)+4*(l>>5).
  float sv[2][16];
#pragma unroll
  for (int it = 0; it < 2; ++it) {
#pragma unroll
    for (int rg = 0; rg < 16; ++rg) sv[it][rg] = 0.f;
    const int p0 = (row0 + w * 64 + it * 32) >> 4;  // 16-row pair index
#pragma unroll
    for (int jt = 0; jt < 4; ++jt) {
      int n = col0 + jt * 32 + (l & 31);
      float b1v = b1[n], w2v = W2[n];
      // sum the two split-K partials of Hs
      float add0 = HsIn[(size_t)p0 * 1024 + n] +
                   HsIn[4194304 + (size_t)p0 * 1024 + n] + b1v;  // rows 0..15
      float add1 = HsIn[(size_t)(p0 + 1) * 1024 + n] +
                   HsIn[4194304 + (size_t)(p0 + 1) * 1024 + n] + b1v;  // 16..31
#pragma unroll
      for (int rg = 0; rg < 16; ++rg) {
        float h = fmaxf(acc[it][jt][rg] + (rg < 8 ? add0 : add1), 0.f);
        sv[it][rg] = fmaf(h, w2v, sv[it][rg]);
      }
    }
  }
  __syncthreads();  // all K-loop LDS reads complete; reuse lds as f32 scratch
  float* scf = (float*)lds;  // 8 slots x 32 x 32 floats = 32KB
  const int cc0 = l & 31, lh4 = 4 * (l >> 5);
#pragma unroll
  for (int it = 0; it < 2; ++it)
#pragma unroll
    for (int rg = 0; rg < 16; ++rg) {
      int row = (rg & 3) + 8 * (rg >> 2) + lh4;  // 0..31 within 32-row block
      scf[((w * 2 + it) * 32 + row) * 32 + ((cc0 + row) & 31)] = sv[it][rg];
    }
  __syncthreads();
  // one thread per global row: sum that row's 32 rotated cols
  int gr = tid;                       // 0..255
  int wv = gr >> 6, itv = (gr >> 5) & 1, r = gr & 31;
  const float* srow = scf + ((wv * 2 + itv) * 32 + r) * 32;
  float sum = 0.f;
#pragma unroll
  for (int j = 0; j < 32; ++j) sum += srow[(j + r) & 31];
  Out[(size_t)cb * 65536 + row0 + gr] = sum;
}

// ---------------------------------------------------------------------------
// Finalize: sum 8 col-block partials (float4 loads), +b2; masked BCE loss;
// argmax preds.  64 blocks x 64 threads.
// ---------------------------------------------------------------------------
__global__ __launch_bounds__(64) void k_final8(const float* __restrict__ score8,
                                               const float* __restrict__ b2p,
                                               const float* __restrict__ targets_all,
                                               const int* __restrict__ linker,
                                               const int* __restrict__ len_all,
                                               float* __restrict__ out) {
  int p = blockIdx.x * 64 + threadIdx.x;  // [0, 4096)
  float b2 = b2p[0];
  int b = p >> 9;
  int i = linker[p];
  int len = len_all[(b << 12) + i];
  const float* tg = targets_all + ((((size_t)b << 12) + (size_t)i) << 4);

  float sc[16];
#pragma unroll
  for (int c = 0; c < 16; ++c) sc[c] = b2;
#pragma unroll
  for (int c8 = 0; c8 < 8; ++c8) {
    const float4* q4 = (const float4*)(score8 + (size_t)c8 * 65536 + p * 16);
#pragma unroll
    for (int j = 0; j < 4; ++j) {
      float4 v = q4[j];
      sc[j * 4 + 0] += v.x; sc[j * 4 + 1] += v.y;
      sc[j * 4 + 2] += v.z; sc[j * 4 + 3] += v.w;
    }
  }

  float loss = 0.f;
  float best = -INFINITY;
  int bc = 0;
#pragma unroll
  for (int c = 0; c < 16; ++c) {
    float s = sc[c];
    out[1 + p * 16 + c] = s;
    float val;
    if (c < len) {
      float t = tg[c];
      loss += fmaxf(s, 0.f) - s * t + log1pf(expf(-fabsf(s)));
      val = s;
    } else {
      val = s - 1e23f;
    }
    if (val > best) { best = val; bc = c; }
  }
  out[1 + 65536 + p] = (float)bc;

  for (int off = 32; off > 0; off >>= 1) loss += __shfl_down(loss, off, 64);
  if (threadIdx.x == 0) atomicAdd(out, loss);
}

// ===========================================================================
// Fallback fp32 path (round-1, proven) — used if ws_size is too small.
// ===========================================================================
#define BM 128
#define BN 128
#define BK 16
#define PAD 4

__global__ __launch_bounds__(256) void k_prep(const int* __restrict__ linker,
                                              const int* __restrict__ cand_all,
                                              int* __restrict__ cand_ids) {
  int g = blockIdx.x * 256 + threadIdx.x;
  int pair = g >> 4;
  int c = g & 15;
  int b = pair >> 9;
  int i = linker[pair];
  cand_ids[g] = cand_all[(((size_t)b << 12) + (size_t)i) * 16 + c];
}

__global__ __launch_bounds__(256) void k_hs(const float* __restrict__ span,
                                            const float* __restrict__ W1,
                                            const int* __restrict__ linker,
                                            float* __restrict__ Hs) {
  const int tid = threadIdx.x;
  const int tx = tid & 15, ty = tid >> 4;
  const int row0 = blockIdx.y * BM;
  const int col0 = blockIdx.x * BN;
  __shared__ float As[BK][BM + PAD];
  __shared__ float Bs[BK][BN + PAD];
  __shared__ int rows_g[BM];
  if (tid < BM) {
    int m = row0 + tid;
    int b = m >> 9;
    rows_g[tid] = (b << 12) + linker[m];
  }
  __syncthreads();
  float acc[8][8] = {};
  for (int k0 = 0; k0 < 1024; k0 += BK) {
#pragma unroll
    for (int ll = 0; ll < 2; ++ll) {
      int f = tid + ll * 256;
      int r = f >> 2;
      int kk = (f & 3) << 2;
      const float4 v = *(const float4*)(span + (size_t)rows_g[r] * 1024 + k0 + kk);
      As[kk + 0][r] = v.x; As[kk + 1][r] = v.y;
      As[kk + 2][r] = v.z; As[kk + 3][r] = v.w;
    }
#pragma unroll
    for (int ll = 0; ll < 2; ++ll) {
      int f = tid + ll * 256;
      int kk = f >> 5;
      int nn = (f & 31) << 2;
      *(float4*)&Bs[kk][nn] = *(const float4*)(W1 + (size_t)(k0 + kk) * 1024 + col0 + nn);
    }
    __syncthreads();
#pragma unroll
    for (int k = 0; k < BK; ++k) {
      float a[8], b[8];
      *(float4*)&a[0] = *(const float4*)&As[k][ty * 8];
      *(float4*)&a[4] = *(const float4*)&As[k][ty * 8 + 4];
      *(float4*)&b[0] = *(const float4*)&Bs[k][tx * 8];
      *(float4*)&b[4] = *(const float4*)&Bs[k][tx * 8 + 4];
#pragma unroll
      for (int i = 0; i < 8; ++i)
#pragma unroll
        for (int j = 0; j < 8; ++j) acc[i][j] = fmaf(a[i], b[j], acc[i][j]);
    }
    __syncthreads();
  }
#pragma unroll
  for (int i = 0; i < 8; ++i) {
    int m = row0 + ty * 8 + i;
    float* dst = Hs + (size_t)m * 1024 + col0 + tx * 8;
    *(float4*)dst = *(float4*)&acc[i][0];
    *(float4*)(dst + 4) = *(float4*)&acc[i][4];
  }
}

__global__ __launch_bounds__(256) void k_hc(const float* __restrict__ ent,
                                            const float* __restrict__ W1,
                                            const int* __restrict__ cand_ids,
                                            const float* __restrict__ Hs,
                                            const float* __restrict__ b1,
                                            const float* __restrict__ W2,
                                            float* __restrict__ score_ws) {
  const int tid = threadIdx.x;
  const int tx = tid & 15, ty = tid >> 4;
  const int row0 = blockIdx.y * BM;
  const int col0 = blockIdx.x * BN;
  __shared__ float As[BK][BM + PAD];
  __shared__ float Bs[BK][BN + PAD];
  __shared__ int rows_g[BM];
  __shared__ float red[BM][17];
  if (tid < BM) rows_g[tid] = cand_ids[row0 + tid];
  __syncthreads();
  float acc[8][8] = {};
  for (int k0 = 0; k0 < 256; k0 += BK) {
#pragma unroll
    for (int ll = 0; ll < 2; ++ll) {
      int f = tid + ll * 256;
      int r = f >> 2;
      int kk = (f & 3) << 2;
      const float4 v = *(const float4*)(ent + (size_t)rows_g[r] * 256 + k0 + kk);
      As[kk + 0][r] = v.x; As[kk + 1][r] = v.y;
      As[kk + 2][r] = v.z; As[kk + 3][r] = v.w;
    }
#pragma unroll
    for (int ll = 0; ll < 2; ++ll) {
      int f = tid + ll * 256;
      int kk = f >> 5;
      int nn = (f & 31) << 2;
      *(float4*)&Bs[kk][nn] =
          *(const float4*)(W1 + (size_t)(1024 + k0 + kk) * 1024 + col0 + nn);
    }
    __syncthreads();
#pragma unroll
    for (int k = 0; k < BK; ++k) {
      float a[8], b[8];
      *(float4*)&a[0] = *(const float4*)&As[k][ty * 8];
      *(float4*)&a[4] = *(const float4*)&As[k][ty * 8 + 4];
      *(float4*)&b[0] = *(const float4*)&Bs[k][tx * 8];
      *(float4*)&b[4] = *(const float4*)&Bs[k][tx * 8 + 4];
#pragma unroll
      for (int i = 0; i < 8; ++i)
#pragma unroll
        for (int j = 0; j < 8; ++j) acc[i][j] = fmaf(a[i], b[j], acc[i][j]);
    }
    __syncthreads();
  }
  const int pair = (row0 + ty * 8) >> 4;
  float hsv[8], b1v[8], w2v[8];
  {
    const float* hp = Hs + (size_t)pair * 1024 + col0 + tx * 8;
    *(float4*)&hsv[0] = *(const float4*)hp;
    *(float4*)&hsv[4] = *(const float4*)(hp + 4);
    const float* bp = b1 + col0 + tx * 8;
    *(float4*)&b1v[0] = *(const float4*)bp;
    *(float4*)&b1v[4] = *(const float4*)(bp + 4);
    const float* wp = W2 + col0 + tx * 8;
    *(float4*)&w2v[0] = *(const float4*)wp;
    *(float4*)&w2v[4] = *(const float4*)(wp + 4);
  }
#pragma unroll
  for (int i = 0; i < 8; ++i) {
    float s = 0.f;
#pragma unroll
    for (int j = 0; j < 8; ++j) {
      float h = acc[i][j] + hsv[j] + b1v[j];
      h = fmaxf(h, 0.f);
      s = fmaf(h, w2v[j], s);
    }
    red[ty * 8 + i][tx] = s;
  }
  __syncthreads();
  if (tid < BM) {
    float s = 0.f;
#pragma unroll
    for (int x = 0; x < 16; ++x) s += red[tid][x];
    atomicAdd(&score_ws[row0 + tid], s);
  }
}

__global__ __launch_bounds__(256) void k_final(const float* __restrict__ score_ws,
                                               const float* __restrict__ b2p,
                                               const float* __restrict__ targets_all,
                                               const int* __restrict__ linker,
                                               const int* __restrict__ len_all,
                                               float* __restrict__ out) {
  int p = blockIdx.x * 256 + threadIdx.x;  // [0, 4096)
  float b2 = b2p[0];
  int b = p >> 9;
  int i = linker[p];
  int len = len_all[(b << 12) + i];
  const float* tg = targets_all + ((((size_t)b << 12) + (size_t)i) << 4);

  float loss = 0.f;
  float best = -INFINITY;
  int bc = 0;
#pragma unroll
  for (int c = 0; c < 16; ++c) {
    float sc = score_ws[p * 16 + c] + b2;
    out[1 + p * 16 + c] = sc;
    float val;
    if (c < len) {
      float t = tg[c];
      loss += fmaxf(sc, 0.f) - sc * t + log1pf(expf(-fabsf(sc)));
      val = sc;
    } else {
      val = sc - 1e23f;
    }
    if (val > best) { best = val; bc = c; }
  }
  out[1 + 65536 + p] = (float)bc;

  for (int off = 32; off > 0; off >>= 1) loss += __shfl_down(loss, off, 64);
  if ((threadIdx.x & 63) == 0) atomicAdd(out, loss);
}

// ===========================================================================
extern "C" void kernel_launch(void* const* d_in, const int* in_sizes, int n_in,
                              void* d_out, int out_size, void* d_ws,
                              size_t ws_size, hipStream_t stream) {
  const float* span    = (const float*)d_in[0];
  const float* ent     = (const float*)d_in[1];
  const float* W1      = (const float*)d_in[2];
  const float* b1      = (const float*)d_in[3];
  const float* W2      = (const float*)d_in[4];
  const float* b2      = (const float*)d_in[5];
  const float* targets = (const float*)d_in[6];
  const int* linker    = (const int*)d_in[7];
  const int* cand_all  = (const int*)d_in[8];
  const int* len_all   = (const int*)d_in[9];
  float* out = (float*)d_out;

  char* ws = (char*)d_ws;
  float* Hs       = (float*)(ws + 0);                  // 33,554,432 (2 split-K partials)
  float* score8   = (float*)(ws + 33554432);           //  2,097,152
  unsigned short* A2   = (unsigned short*)(ws + 35651584);  // 33,554,432 (fp16)
  unsigned short* sTh  = (unsigned short*)(ws + 69206016);  //  2,097,152
  unsigned short* sTl  = (unsigned short*)(ws + 71303168);  //  2,097,152
  unsigned short* eT16 = (unsigned short*)(ws + 73400320);  //    524,288 (fp16)
  float* score_ws = (float*)(ws + 73924608);           //    262,144 (fallback)
  int* cand_ids   = (int*)(ws + 74186752);             //    262,144 (fallback)
  const size_t NEED_MFMA = 74448896;

  hipMemsetAsync(d_out, 0, sizeof(float), stream);

  if (ws_size >= NEED_MFMA) {
    // prep: ent gather -> fp16 A2 (BW-bound prematerialization) + W1^T
    k_prep_e<<<dim3(17664), dim3(256), 0, stream>>>(
        ent, W1, linker, cand_all, A2, sTh, sTl, eT16);
    // GEMM1: Hs partials = gather(span)@W1s, split-2 bf16, split-K x2
    k_g32g<16><<<dim3(512), dim3(256), 0, stream>>>(span, linker, sTh, sTl, Hs);
    // GEMM2 v2: A2@W1e fp16, 256x128 tile + relu + W2 row-sums
    k_gf16<<<dim3(2048), dim3(256), 0, stream>>>(A2, eT16, Hs, b1, W2, score8);
    k_final8<<<dim3(64), dim3(64), 0, stream>>>(score8, b2, targets, linker,
                                                len_all, out);
  } else {
    hipMemsetAsync(score_ws, 0, 65536 * sizeof(float), stream);
    k_prep<<<dim3(256), dim3(256), 0, stream>>>(linker, cand_all, cand_ids);
    dim3 g1(8, 32);
    k_hs<<<g1, dim3(256), 0, stream>>>(span, W1, linker, Hs);
    dim3 g2(8, 512);
    k_hc<<<g2, dim3(256), 0, stream>>>(ent, W1, cand_ids, Hs, b1, W2, score_ws);
    k_final<<<dim3(16), dim3(256), 0, stream>>>(score_ws, b2, targets, linker,
                                                len_all, out);
  }
}

// Round 8
// 328.528 us; speedup vs baseline: 1.0436x; 1.0072x over previous
//
#include <hip/hip_runtime.h>
#include <math.h>

// B=8, N=4096, S=512, C=16, D=1024, E=256, H=1024, V=100000
// d_out (float32): [0]=loss, [1..65536]=scores (8,512,16), [65537..69632]=preds

typedef short short8 __attribute__((ext_vector_type(8)));
typedef _Float16 half8v __attribute__((ext_vector_type(8)));
typedef float f32x16 __attribute__((ext_vector_type(16)));

static __device__ inline unsigned short f2bf(float x) {
  unsigned u = __float_as_uint(x);
  unsigned r = (u + 0x7FFFu + ((u >> 16) & 1u)) >> 16;
  return (unsigned short)r;
}
static __device__ inline float bf2f(unsigned short b) {
  return __uint_as_float(((unsigned)b) << 16);
}
static __device__ inline unsigned short f2h(float x) {
  _Float16 h = (_Float16)x;  // v_cvt_f16_f32, RTE
  return *(unsigned short*)&h;
}

#define GLD_TO_LDS(gp, lp)                                          \
  __builtin_amdgcn_global_load_lds(                                 \
      (const __attribute__((address_space(1))) void*)(gp),          \
      (__attribute__((address_space(3))) void*)(lp), 16, 0, 0)

// Split 8 gathered fp32 into bf16 hi/lo and write both LDS regions
// (chunk g -> ushort offset g*8; Alo region at +4096).
static __device__ inline void split_write(unsigned short* buf, int g,
                                          float4 c0, float4 c1) {
  float xs[8] = {c0.x, c0.y, c0.z, c0.w, c1.x, c1.y, c1.z, c1.w};
  short8 h8, l8;
#pragma unroll
  for (int j = 0; j < 8; ++j) {
    unsigned short h = f2bf(xs[j]);
    h8[j] = (short)h;
    l8[j] = (short)f2bf(xs[j] - bf2f(h));
  }
  *(short8*)(buf + (g << 3)) = h8;
  *(short8*)(buf + 4096 + (g << 3)) = l8;
}

// ---------------------------------------------------------------------------
// Fused prep: ent gather -> fp16 A2 (scattered reads off the 102MB table are
// prematerialized at pure BW -- round-4 lesson: in-GEMM gather of >L2 data is
// latency-bound), plus W1 transpose.
//   blocks [0, 16384)       : ent gather -> fp16 A2 (65536 x 256)
//   blocks [16384, 17664)   : W1^T -> sT split-2 bf16 / eT fp16
// ---------------------------------------------------------------------------
__global__ __launch_bounds__(256) void k_prep_e(
    const float* __restrict__ ent, const float* __restrict__ W1,
    const int* __restrict__ linker, const int* __restrict__ cand_all,
    unsigned short* __restrict__ A2, unsigned short* __restrict__ sThi,
    unsigned short* __restrict__ sTlo, unsigned short* __restrict__ eT16) {
  __shared__ float t[32][33];  // only used by the w1t branch
  const int bx = blockIdx.x;
  if (bx < 16384) {
    // ---- ent gather -> fp16.  f indexes float4s of 65536 rows x 256 cols.
    int f = bx * 256 + threadIdx.x;
    int row = f >> 6;        // candidate slot [0, 65536)
    int pair = row >> 4;     // [0, 4096)
    int b = pair >> 9;
    int i = linker[pair];
    int cid = cand_all[(((size_t)b << 12) + (size_t)i) * 16 + (row & 15)];
    const float4 v = *((const float4*)(ent + ((size_t)cid << 8)) + (f & 63));
    *(ushort4*)(A2 + ((size_t)f << 2)) =
        make_ushort4(f2h(v.x), f2h(v.y), f2h(v.z), f2h(v.w));
  } else {
    // ---- W1 (1280x1024) transpose: span part split-2 bf16, ent part fp16.
    int b2x = bx - 16384;           // [0, 1280) = 32 n-tiles x 40 k-tiles
    int n0 = (b2x & 31) * 32, k0 = (b2x >> 5) * 32;
    int rr = threadIdx.x >> 5, cc = threadIdx.x & 31;
#pragma unroll
    for (int i = 0; i < 4; ++i)
      t[rr + 8 * i][cc] = W1[(size_t)(k0 + rr + 8 * i) * 1024 + n0 + cc];
    __syncthreads();
#pragma unroll
    for (int i = 0; i < 4; ++i) {
      int nl = rr + 8 * i;
      float v = t[cc][nl];
      int n = n0 + nl, k = k0 + cc;
      if (k0 < 1024) {
        unsigned short h = f2bf(v);
        unsigned short l = f2bf(v - bf2f(h));
        sThi[(size_t)n * 1024 + k] = h;
        sTlo[(size_t)n * 1024 + k] = l;
      } else {
        eT16[(size_t)n * 256 + (k - 1024)] = f2h(v);
      }
    }
  }
}

// ---------------------------------------------------------------------------
// GEMM1: split-2 bf16 MFMA, 128x128 tile, BK=32, split-K x2 (grid 512).
// A is gathered DIRECTLY from span (per-lane fp32 loads via linker -- L2-
// friendly 16MB working set, compute phase 48 MFMAs covers the latency),
// split to bf16 hi/lo in-register, ds_write'd into the swizzled LDS layout.
// B (W1s^T) staged via global_load_lds from the preconverted split buffers.
// ---------------------------------------------------------------------------
template <int KSTEPS>
__global__ __launch_bounds__(256, 2) void k_g32g(
    const float* __restrict__ span, const int* __restrict__ linker,
    const unsigned short* __restrict__ Bhi, const unsigned short* __restrict__ Blo,
    float* __restrict__ Out) {
  const int tid = threadIdx.x;
  const int l = tid & 63;
  const int w = tid >> 6;        // 0..3
  const int wm = w >> 1, wn = w & 1;
  const int id = blockIdx.x;
  const int z = id >> 8;         // K-split index
  const int sid = id & 255;
  const int m8 = sid & 7;
  const int cb = (sid >> 3) & 7;
  const int q = sid >> 6;
  const int row0 = ((q << 3) + m8) << 7;
  const int col0 = cb << 7;
  const int koff = z * (KSTEPS * 32);
  Out += (size_t)z * 4194304;

  // Two buffers of 16384 ushorts (32KB) each:
  // Ahi[0..4095] | Alo[4096..] | Bhi[8192..] | Blo[12288..]
  __shared__ unsigned short lds[32768];

  f32x16 acc[2][2];
#pragma unroll
  for (int i = 0; i < 2; ++i)
#pragma unroll
    for (int j = 0; j < 2; ++j)
#pragma unroll
      for (int k = 0; k < 16; ++k) acc[i][j][k] = 0.f;

  const int ar0 = tid >> 2, ap0 = tid & 3;
  const int al0c = ap0 ^ ((ar0 >> 1) & 3);
  const int ar1 = ar0 + 64;
  const int al1c = ap0 ^ ((ar1 >> 1) & 3);
  // gathered A source rows (b constant per 128-row tile since 128 | 512)
  const int r0g = row0 + ar0, r1g = row0 + ar1;
  const float* asrc0 =
      span + (((size_t)(r0g >> 9) << 12) + linker[r0g]) * 1024 + koff + al0c * 8;
  const float* asrc1 =
      span + (((size_t)(r1g >> 9) << 12) + linker[r1g]) * 1024 + koff + al1c * 8;
  const size_t boff0 = (size_t)(col0 + ar0) * 1024 + al0c * 8 + koff;
  const size_t boff1 = (size_t)(col0 + ar1) * 1024 + al1c * 8 + koff;
  const int w512 = w * 512;

  // ---- prologue: stage K-step 0 into buffer 0
  {
    float4 a00 = *(const float4*)(asrc0);
    float4 a01 = *(const float4*)(asrc0 + 4);
    float4 a10 = *(const float4*)(asrc1);
    float4 a11 = *(const float4*)(asrc1 + 4);
    GLD_TO_LDS(Bhi + boff0, lds + 8192 + w512);
    GLD_TO_LDS(Bhi + boff1, lds + 10240 + w512);
    GLD_TO_LDS(Blo + boff0, lds + 12288 + w512);
    GLD_TO_LDS(Blo + boff1, lds + 14336 + w512);
    split_write(lds, tid, a00, a01);
    split_write(lds, tid + 256, a10, a11);
  }
  asm volatile("s_waitcnt vmcnt(0) lgkmcnt(0)" ::: "memory");
  __builtin_amdgcn_s_barrier();
  asm volatile("" ::: "memory");

  for (int ks = 0; ks < KSTEPS; ++ks) {
    float4 a00, a01, a10, a11;
    const int k0n = (ks + 1) * 32;
    unsigned short* bn = lds + (((ks + 1) & 1) << 14);
    if (ks + 1 < KSTEPS) {
      a00 = *(const float4*)(asrc0 + k0n);
      a01 = *(const float4*)(asrc0 + k0n + 4);
      a10 = *(const float4*)(asrc1 + k0n);
      a11 = *(const float4*)(asrc1 + k0n + 4);
      GLD_TO_LDS(Bhi + boff0 + k0n, bn + 8192 + w512);
      GLD_TO_LDS(Bhi + boff1 + k0n, bn + 10240 + w512);
      GLD_TO_LDS(Blo + boff0 + k0n, bn + 12288 + w512);
      GLD_TO_LDS(Blo + boff1 + k0n, bn + 14336 + w512);
    }

    const unsigned short* cbuf = lds + ((ks & 1) << 14);
#pragma unroll
    for (int kc = 0; kc < 2; ++kc) {
      const int kg = kc * 2 + (l >> 5);
      short8 ah[2], alv[2], bh[2], bl[2];
#pragma unroll
      for (int it = 0; it < 2; ++it) {
        int r = wm * 64 + it * 32 + (l & 31);
        int off = r * 32 + ((kg ^ ((r >> 1) & 3)) << 3);
        ah[it] = *(const short8*)(cbuf + off);
        alv[it] = *(const short8*)(cbuf + 4096 + off);
      }
#pragma unroll
      for (int jt = 0; jt < 2; ++jt) {
        int r = wn * 64 + jt * 32 + (l & 31);
        int off = r * 32 + ((kg ^ ((r >> 1) & 3)) << 3);
        bh[jt] = *(const short8*)(cbuf + 8192 + off);
        bl[jt] = *(const short8*)(cbuf + 12288 + off);
      }
#pragma unroll
      for (int it = 0; it < 2; ++it)
#pragma unroll
        for (int jt = 0; jt < 2; ++jt) {
          acc[it][jt] = __builtin_amdgcn_mfma_f32_32x32x16_bf16(
              ah[it], bh[jt], acc[it][jt], 0, 0, 0);
          acc[it][jt] = __builtin_amdgcn_mfma_f32_32x32x16_bf16(
              ah[it], bl[jt], acc[it][jt], 0, 0, 0);
          acc[it][jt] = __builtin_amdgcn_mfma_f32_32x32x16_bf16(
              alv[it], bh[jt], acc[it][jt], 0, 0, 0);
        }
    }

    if (ks + 1 < KSTEPS) {
      split_write(bn, tid, a00, a01);
      split_write(bn, tid + 256, a10, a11);
      asm volatile("s_waitcnt vmcnt(0) lgkmcnt(0)" ::: "memory");
      __builtin_amdgcn_s_barrier();
      asm volatile("" ::: "memory");
    }
  }

  // C/D layout (32x32): col = l&31, row = (rg&3) + 8*(rg>>2) + 4*(l>>5)
#pragma unroll
  for (int it = 0; it < 2; ++it) {
    int mb = row0 + wm * 64 + it * 32 + 4 * (l >> 5);
#pragma unroll
    for (int jt = 0; jt < 2; ++jt) {
      int n = col0 + wn * 64 + jt * 32 + (l & 31);
#pragma unroll
      for (int rg = 0; rg < 16; ++rg) {
        int m = mb + (rg & 3) + 8 * (rg >> 2);
        Out[(size_t)m * 1024 + n] = acc[it][jt][rg];
      }
    }
  }
}

// ---------------------------------------------------------------------------
// GEMM2 v3: plain fp16 MFMA (32x32x16_f16), 256x128 tile, BK=32, K=256.
// T4 counted-vmcnt pipeline: THREE 24KB LDS buffers (72KB -> 2 blocks/CU),
// 2-deep prefetch; bottom-of-step waits vmcnt(6) (NOT 0) so the next-next
// step's 6 global_load_lds stay in flight across the barrier -- two compute
// phases cover each load's HBM latency.  T5: setprio(1) around the MFMA
// cluster (counted pipeline creates the load/MFMA wave role split).
// Fused epilogue: relu(acc + (Hs0+Hs1) + b1).W2 row-sums -> per-cb partials.
// Grid 2048, XCD-swizzled.
// ---------------------------------------------------------------------------
__global__ __launch_bounds__(256, 2) void k_gf16(
    const unsigned short* __restrict__ A,    // fp16 bits, 65536 x 256
    const unsigned short* __restrict__ Bt,   // fp16 bits, 1024 x 256
    const float* __restrict__ HsIn, const float* __restrict__ b1,
    const float* __restrict__ W2, float* __restrict__ Out) {
  const int tid = threadIdx.x;
  const int l = tid & 63;
  const int w = tid >> 6;        // 0..3, wave owns rows w*64..w*64+63
  const int id = blockIdx.x;
  const int m8 = id & 7;
  const int cb = (id >> 3) & 7;
  const int q = id >> 6;         // 0..31
  const int row0 = ((q << 3) + m8) << 8;   // 256-row tile
  const int col0 = cb << 7;

  // Three buffers of 12288 ushorts (24KB): A[0..8191] | B[8192..12287]
  __shared__ unsigned short lds[36864];

  f32x16 acc[2][4];
#pragma unroll
  for (int i = 0; i < 2; ++i)
#pragma unroll
    for (int j = 0; j < 4; ++j)
#pragma unroll
      for (int k = 0; k < 16; ++k) acc[i][j][k] = 0.f;

  // Chunk swizzle: chunk g covers row r=g>>2, logical K-slot c = (g&3)^((r>>1)&3).
  const int ar = tid >> 2, ap = tid & 3;
  const int ac = ap ^ ((ar >> 1) & 3);
  const size_t abase = (size_t)(row0 + ar) * 256 + ac * 8;  // +16384 per +64 rows
  const size_t bbase = (size_t)(col0 + ar) * 256 + ac * 8;
  const int w512 = w * 512;

#define STAGE2(buf, ks32)                                         \
  do {                                                            \
    GLD_TO_LDS(A + abase + (ks32), (buf) + w512);                 \
    GLD_TO_LDS(A + abase + 16384 + (ks32), (buf) + 2048 + w512);  \
    GLD_TO_LDS(A + abase + 32768 + (ks32), (buf) + 4096 + w512);  \
    GLD_TO_LDS(A + abase + 49152 + (ks32), (buf) + 6144 + w512);  \
    GLD_TO_LDS(Bt + bbase + (ks32), (buf) + 8192 + w512);         \
    GLD_TO_LDS(Bt + bbase + 16384 + (ks32), (buf) + 10240 + w512);\
  } while (0)

  // ---- prologue: stage K-steps 0 and 1 (2-deep), wait only for step 0
  STAGE2(lds, 0);
  STAGE2(lds + 12288, 32);
  asm volatile("s_waitcnt vmcnt(6)" ::: "memory");
  __builtin_amdgcn_s_barrier();
  asm volatile("" ::: "memory");

#pragma unroll
  for (int ks = 0; ks < 8; ++ks) {
    if (ks + 2 < 8) {
      unsigned short* bn = lds + ((ks + 2) % 3) * 12288;
      STAGE2(bn, (ks + 2) * 32);
    }

    const unsigned short* cbuf = lds + (ks % 3) * 12288;
#pragma unroll
    for (int kc = 0; kc < 2; ++kc) {
      const int kg = kc * 2 + (l >> 5);
      half8v av[2], bv[4];
#pragma unroll
      for (int it = 0; it < 2; ++it) {
        int r = w * 64 + it * 32 + (l & 31);
        int off = r * 32 + ((kg ^ ((r >> 1) & 3)) << 3);
        av[it] = *(const half8v*)(cbuf + off);
      }
#pragma unroll
      for (int jt = 0; jt < 4; ++jt) {
        int r = jt * 32 + (l & 31);
        int off = 8192 + r * 32 + ((kg ^ ((r >> 1) & 3)) << 3);
        bv[jt] = *(const half8v*)(cbuf + off);
      }
      __builtin_amdgcn_s_setprio(1);
#pragma unroll
      for (int it = 0; it < 2; ++it)
#pragma unroll
        for (int jt = 0; jt < 4; ++jt)
          acc[it][jt] = __builtin_amdgcn_mfma_f32_32x32x16_f16(
              av[it], bv[jt], acc[it][jt], 0, 0, 0);
      __builtin_amdgcn_s_setprio(0);
    }

    if (ks + 1 < 8) {
      // need buffer (ks+1) resident; leave (ks+2)'s 6 loads in flight
      if (ks + 2 < 8) {
        asm volatile("s_waitcnt vmcnt(6)" ::: "memory");
      } else {
        asm volatile("s_waitcnt vmcnt(0)" ::: "memory");
      }
      __builtin_amdgcn_s_barrier();
      asm volatile("" ::: "memory");
    }
  }
#undef STAGE2

  // Fused epilogue: per-lane partial scores (summed over this lane's 4 jt
  // cols), then LDS transpose-reduce (8 slots x 32 rows x 32 cols, rotation-
  // swizzled).  C/D: col = l&31, row = (rg&3)+8*(rg>>2)+4*(l>>5).
  float sv[2][16];
#pragma unroll
  for (int it = 0; it < 2; ++it) {
#pragma unroll
    for (int rg = 0; rg < 16; ++rg) sv[it][rg] = 0.f;
    const int p0 = (row0 + w * 64 + it * 32) >> 4;  // 16-row pair index
#pragma unroll
    for (int jt = 0; jt < 4; ++jt) {
      int n = col0 + jt * 32 + (l & 31);
      float b1v = b1[n], w2v = W2[n];
      // sum the two split-K partials of Hs
      float add0 = HsIn[(size_t)p0 * 1024 + n] +
                   HsIn[4194304 + (size_t)p0 * 1024 + n] + b1v;  // rows 0..15
      float add1 = HsIn[(size_t)(p0 + 1) * 1024 + n] +
                   HsIn[4194304 + (size_t)(p0 + 1) * 1024 + n] + b1v;  // 16..31
#pragma unroll
      for (int rg = 0; rg < 16; ++rg) {
        float h = fmaxf(acc[it][jt][rg] + (rg < 8 ? add0 : add1), 0.f);
        sv[it][rg] = fmaf(h, w2v, sv[it][rg]);
      }
    }
  }
  __syncthreads();  // all K-loop LDS reads complete; reuse lds as f32 scratch
  float* scf = (float*)lds;  // 8 slots x 32 x 32 floats = 32KB
  const int cc0 = l & 31, lh4 = 4 * (l >> 5);
#pragma unroll
  for (int it = 0; it < 2; ++it)
#pragma unroll
    for (int rg = 0; rg < 16; ++rg) {
      int row = (rg & 3) + 8 * (rg >> 2) + lh4;  // 0..31 within 32-row block
      scf[((w * 2 + it) * 32 + row) * 32 + ((cc0 + row) & 31)] = sv[it][rg];
    }
  __syncthreads();
  // one thread per global row: sum that row's 32 rotated cols
  int gr = tid;                       // 0..255
  int wv = gr >> 6, itv = (gr >> 5) & 1, r = gr & 31;
  const float* srow = scf + ((wv * 2 + itv) * 32 + r) * 32;
  float sum = 0.f;
#pragma unroll
  for (int j = 0; j < 32; ++j) sum += srow[(j + r) & 31];
  Out[(size_t)cb * 65536 + row0 + gr] = sum;
}

// ---------------------------------------------------------------------------
// Finalize: sum 8 col-block partials (float4 loads), +b2; masked BCE loss;
// argmax preds.  64 blocks x 64 threads.
// ---------------------------------------------------------------------------
__global__ __launch_bounds__(64) void k_final8(const float* __restrict__ score8,
                                               const float* __restrict__ b2p,
                                               const float* __restrict__ targets_all,
                                               const int* __restrict__ linker,
                                               const int* __restrict__ len_all,
                                               float* __restrict__ out) {
  int p = blockIdx.x * 64 + threadIdx.x;  // [0, 4096)
  float b2 = b2p[0];
  int b = p >> 9;
  int i = linker[p];
  int len = len_all[(b << 12) + i];
  const float* tg = targets_all + ((((size_t)b << 12) + (size_t)i) << 4);

  float sc[16];
#pragma unroll
  for (int c = 0; c < 16; ++c) sc[c] = b2;
#pragma unroll
  for (int c8 = 0; c8 < 8; ++c8) {
    const float4* q4 = (const float4*)(score8 + (size_t)c8 * 65536 + p * 16);
#pragma unroll
    for (int j = 0; j < 4; ++j) {
      float4 v = q4[j];
      sc[j * 4 + 0] += v.x; sc[j * 4 + 1] += v.y;
      sc[j * 4 + 2] += v.z; sc[j * 4 + 3] += v.w;
    }
  }

  float loss = 0.f;
  float best = -INFINITY;
  int bc = 0;
#pragma unroll
  for (int c = 0; c < 16; ++c) {
    float s = sc[c];
    out[1 + p * 16 + c] = s;
    float val;
    if (c < len) {
      float t = tg[c];
      loss += fmaxf(s, 0.f) - s * t + log1pf(expf(-fabsf(s)));
      val = s;
    } else {
      val = s - 1e23f;
    }
    if (val > best) { best = val; bc = c; }
  }
  out[1 + 65536 + p] = (float)bc;

  for (int off = 32; off > 0; off >>= 1) loss += __shfl_down(loss, off, 64);
  if (threadIdx.x == 0) atomicAdd(out, loss);
}

// ===========================================================================
// Fallback fp32 path (round-1, proven) — used if ws_size is too small.
// ===========================================================================
#define BM 128
#define BN 128
#define BK 16
#define PAD 4

__global__ __launch_bounds__(256) void k_prep(const int* __restrict__ linker,
                                              const int* __restrict__ cand_all,
                                              int* __restrict__ cand_ids) {
  int g = blockIdx.x * 256 + threadIdx.x;
  int pair = g >> 4;
  int c = g & 15;
  int b = pair >> 9;
  int i = linker[pair];
  cand_ids[g] = cand_all[(((size_t)b << 12) + (size_t)i) * 16 + c];
}

__global__ __launch_bounds__(256) void k_hs(const float* __restrict__ span,
                                            const float* __restrict__ W1,
                                            const int* __restrict__ linker,
                                            float* __restrict__ Hs) {
  const int tid = threadIdx.x;
  const int tx = tid & 15, ty = tid >> 4;
  const int row0 = blockIdx.y * BM;
  const int col0 = blockIdx.x * BN;
  __shared__ float As[BK][BM + PAD];
  __shared__ float Bs[BK][BN + PAD];
  __shared__ int rows_g[BM];
  if (tid < BM) {
    int m = row0 + tid;
    int b = m >> 9;
    rows_g[tid] = (b << 12) + linker[m];
  }
  __syncthreads();
  float acc[8][8] = {};
  for (int k0 = 0; k0 < 1024; k0 += BK) {
#pragma unroll
    for (int ll = 0; ll < 2; ++ll) {
      int f = tid + ll * 256;
      int r = f >> 2;
      int kk = (f & 3) << 2;
      const float4 v = *(const float4*)(span + (size_t)rows_g[r] * 1024 + k0 + kk);
      As[kk + 0][r] = v.x; As[kk + 1][r] = v.y;
      As[kk + 2][r] = v.z; As[kk + 3][r] = v.w;
    }
#pragma unroll
    for (int ll = 0; ll < 2; ++ll) {
      int f = tid + ll * 256;
      int kk = f >> 5;
      int nn = (f & 31) << 2;
      *(float4*)&Bs[kk][nn] = *(const float4*)(W1 + (size_t)(k0 + kk) * 1024 + col0 + nn);
    }
    __syncthreads();
#pragma unroll
    for (int k = 0; k < BK; ++k) {
      float a[8], b[8];
      *(float4*)&a[0] = *(const float4*)&As[k][ty * 8];
      *(float4*)&a[4] = *(const float4*)&As[k][ty * 8 + 4];
      *(float4*)&b[0] = *(const float4*)&Bs[k][tx * 8];
      *(float4*)&b[4] = *(const float4*)&Bs[k][tx * 8 + 4];
#pragma unroll
      for (int i = 0; i < 8; ++i)
#pragma unroll
        for (int j = 0; j < 8; ++j) acc[i][j] = fmaf(a[i], b[j], acc[i][j]);
    }
    __syncthreads();
  }
#pragma unroll
  for (int i = 0; i < 8; ++i) {
    int m = row0 + ty * 8 + i;
    float* dst = Hs + (size_t)m * 1024 + col0 + tx * 8;
    *(float4*)dst = *(float4*)&acc[i][0];
    *(float4*)(dst + 4) = *(float4*)&acc[i][4];
  }
}

__global__ __launch_bounds__(256) void k_hc(const float* __restrict__ ent,
                                            const float* __restrict__ W1,
                                            const int* __restrict__ cand_ids,
                                            const float* __restrict__ Hs,
                                            const float* __restrict__ b1,
                                            const float* __restrict__ W2,
                                            float* __restrict__ score_ws) {
  const int tid = threadIdx.x;
  const int tx = tid & 15, ty = tid >> 4;
  const int row0 = blockIdx.y * BM;
  const int col0 = blockIdx.x * BN;
  __shared__ float As[BK][BM + PAD];
  __shared__ float Bs[BK][BN + PAD];
  __shared__ int rows_g[BM];
  __shared__ float red[BM][17];
  if (tid < BM) rows_g[tid] = cand_ids[row0 + tid];
  __syncthreads();
  float acc[8][8] = {};
  for (int k0 = 0; k0 < 256; k0 += BK) {
#pragma unroll
    for (int ll = 0; ll < 2; ++ll) {
      int f = tid + ll * 256;
      int r = f >> 2;
      int kk = (f & 3) << 2;
      const float4 v = *(const float4*)(ent + (size_t)rows_g[r] * 256 + k0 + kk);
      As[kk + 0][r] = v.x; As[kk + 1][r] = v.y;
      As[kk + 2][r] = v.z; As[kk + 3][r] = v.w;
    }
#pragma unroll
    for (int ll = 0; ll < 2; ++ll) {
      int f = tid + ll * 256;
      int kk = f >> 5;
      int nn = (f & 31) << 2;
      *(float4*)&Bs[kk][nn] =
          *(const float4*)(W1 + (size_t)(1024 + k0 + kk) * 1024 + col0 + nn);
    }
    __syncthreads();
#pragma unroll
    for (int k = 0; k < BK; ++k) {
      float a[8], b[8];
      *(float4*)&a[0] = *(const float4*)&As[k][ty * 8];
      *(float4*)&a[4] = *(const float4*)&As[k][ty * 8 + 4];
      *(float4*)&b[0] = *(const float4*)&Bs[k][tx * 8];
      *(float4*)&b[4] = *(const float4*)&Bs[k][tx * 8 + 4];
#pragma unroll
      for (int i = 0; i < 8; ++i)
#pragma unroll
        for (int j = 0; j < 8; ++j) acc[i][j] = fmaf(a[i], b[j], acc[i][j]);
    }
    __syncthreads();
  }
  const int pair = (row0 + ty * 8) >> 4;
  float hsv[8], b1v[8], w2v[8];
  {
    const float* hp = Hs + (size_t)pair * 1024 + col0 + tx * 8;
    *(float4*)&hsv[0] = *(const float4*)hp;
    *(float4*)&hsv[4] = *(const float4*)(hp + 4);
    const float* bp = b1 + col0 + tx * 8;
    *(float4*)&b1v[0] = *(const float4*)bp;
    *(float4*)&b1v[4] = *(const float4*)(bp + 4);
    const float* wp = W2 + col0 + tx * 8;
    *(float4*)&w2v[0] = *(const float4*)wp;
    *(float4*)&w2v[4] = *(const float4*)(wp + 4);
  }
#pragma unroll
  for (int i = 0; i < 8; ++i) {
    float s = 0.f;
#pragma unroll
    for (int j = 0; j < 8; ++j) {
      float h = acc[i][j] + hsv[j] + b1v[j];
      h = fmaxf(h, 0.f);
      s = fmaf(h, w2v[j], s);
    }
    red[ty * 8 + i][tx] = s;
  }
  __syncthreads();
  if (tid < BM) {
    float s = 0.f;
#pragma unroll
    for (int x = 0; x < 16; ++x) s += red[tid][x];
    atomicAdd(&score_ws[row0 + tid], s);
  }
}

__global__ __launch_bounds__(256) void k_final(const float* __restrict__ score_ws,
                                               const float* __restrict__ b2p,
                                               const float* __restrict__ targets_all,
                                               const int* __restrict__ linker,
                                               const int* __restrict__ len_all,
                                               float* __restrict__ out) {
  int p = blockIdx.x * 256 + threadIdx.x;  // [0, 4096)
  float b2 = b2p[0];
  int b = p >> 9;
  int i = linker[p];
  int len = len_all[(b << 12) + i];
  const float* tg = targets_all + ((((size_t)b << 12) + (size_t)i) << 4);

  float loss = 0.f;
  float best = -INFINITY;
  int bc = 0;
#pragma unroll
  for (int c = 0; c < 16; ++c) {
    float sc = score_ws[p * 16 + c] + b2;
    out[1 + p * 16 + c] = sc;
    float val;
    if (c < len) {
      float t = tg[c];
      loss += fmaxf(sc, 0.f) - sc * t + log1pf(expf(-fabsf(sc)));
      val = sc;
    } else {
      val = sc - 1e23f;
    }
    if (val > best) { best = val; bc = c; }
  }
  out[1 + 65536 + p] = (float)bc;

  for (int off = 32; off > 0; off >>= 1) loss += __shfl_down(loss, off, 64);
  if ((threadIdx.x & 63) == 0) atomicAdd(out, loss);
}

// ===========================================================================
extern "C" void kernel_launch(void* const* d_in, const int* in_sizes, int n_in,
                              void* d_out, int out_size, void* d_ws,
                              size_t ws_size, hipStream_t stream) {
  const float* span    = (const float*)d_in[0];
  const float* ent     = (const float*)d_in[1];
  const float* W1      = (const float*)d_in[2];
  const float* b1      = (const float*)d_in[3];
  const float* W2      = (const float*)d_in[4];
  const float* b2      = (const float*)d_in[5];
  const float* targets = (const float*)d_in[6];
  const int* linker    = (const int*)d_in[7];
  const int* cand_all  = (const int*)d_in[8];
  const int* len_all   = (const int*)d_in[9];
  float* out = (float*)d_out;

  char* ws = (char*)d_ws;
  float* Hs       = (float*)(ws + 0);                  // 33,554,432 (2 split-K partials)
  float* score8   = (float*)(ws + 33554432);           //  2,097,152
  unsigned short* A2   = (unsigned short*)(ws + 35651584);  // 33,554,432 (fp16)
  unsigned short* sTh  = (unsigned short*)(ws + 69206016);  //  2,097,152
  unsigned short* sTl  = (unsigned short*)(ws + 71303168);  //  2,097,152
  unsigned short* eT16 = (unsigned short*)(ws + 73400320);  //    524,288 (fp16)
  float* score_ws = (float*)(ws + 73924608);           //    262,144 (fallback)
  int* cand_ids   = (int*)(ws + 74186752);             //    262,144 (fallback)
  const size_t NEED_MFMA = 74448896;

  hipMemsetAsync(d_out, 0, sizeof(float), stream);

  if (ws_size >= NEED_MFMA) {
    // prep: ent gather -> fp16 A2 (BW-bound prematerialization) + W1^T
    k_prep_e<<<dim3(17664), dim3(256), 0, stream>>>(
        ent, W1, linker, cand_all, A2, sTh, sTl, eT16);
    // GEMM1: Hs partials = gather(span)@W1s, split-2 bf16, split-K x2
    k_g32g<16><<<dim3(512), dim3(256), 0, stream>>>(span, linker, sTh, sTl, Hs);
    // GEMM2 v3: A2@W1e fp16, 256x128 tile, counted-vmcnt 3-buffer pipeline
    k_gf16<<<dim3(2048), dim3(256), 0, stream>>>(A2, eT16, Hs, b1, W2, score8);
    k_final8<<<dim3(64), dim3(64), 0, stream>>>(score8, b2, targets, linker,
                                                len_all, out);
  } else {
    hipMemsetAsync(score_ws, 0, 65536 * sizeof(float), stream);
    k_prep<<<dim3(256), dim3(256), 0, stream>>>(linker, cand_all, cand_ids);
    dim3 g1(8, 32);
    k_hs<<<g1, dim3(256), 0, stream>>>(span, W1, linker, Hs);
    dim3 g2(8, 512);
    k_hc<<<g2, dim3(256), 0, stream>>>(ent, W1, cand_ids, Hs, b1, W2, score_ws);
    k_final<<<dim3(16), dim3(256), 0, stream>>>(score_ws, b2, targets, linker,
                                                len_all, out);
  }
}